// Round 5
// baseline (1128.946 us; speedup 1.0000x reference)
//
#include <hip/hip_runtime.h>

// Neural HMM forward-algorithm NLL.  K=128, V=50257, D=H=128, B=64, T=2048.
//
//  K1 k_emis : E[v][k] = exp(tag[k]·word[v] + bias[v]) (unnormalized) + partial Z
//  K2 k_trans: A2[i][j] = softmax_j(Wq+b)[i][j] / Z_j ; piZ / piZP (permuted)
//  K3 k_gather: emP[t][b][p] = bf16( E[tok[b,t]][phi^-1(p)] * bump(t) )
//  K4 k_fwd_m2: barrier-free MFMA recursion, 1 wave per 16 batches (4 blocks).
//     State relabeling phi makes D-fragment == next B-fragment lane-locally:
//       phi  : j = 64h+16c+4g+r  ->  p = 32c+8g+4h+r   (bit shuffle)
//     so alpha never leaves registers; A2/em/piZ are pre-permuted.
//  K5 k_final : out = -sum_b ll[b]

#define KK 128
#define TT 2048
#define BB 64

typedef short v8s __attribute__((ext_vector_type(8)));
typedef float v4f __attribute__((ext_vector_type(4)));

__device__ __forceinline__ float wave_sum64(float v) {
#pragma unroll
  for (int m = 32; m; m >>= 1) v += __shfl_xor(v, m, 64);
  return v;
}
__device__ __forceinline__ float wave_max64(float v) {
#pragma unroll
  for (int m = 32; m; m >>= 1) v = fmaxf(v, __shfl_xor(v, m, 64));
  return v;
}
// f32 -> bf16 round-to-nearest-even (positive normals here)
__device__ __forceinline__ unsigned short f2bf(float x) {
  union { float f; unsigned u; } c; c.f = x;
  unsigned r = c.u + 0x7fffu + ((c.u >> 16) & 1u);
  return (unsigned short)(r >> 16);
}
__device__ __forceinline__ float bflo(unsigned u) {
  union { unsigned u; float f; } c; c.u = u << 16; return c.f;
}
__device__ __forceinline__ float bfhi(unsigned u) {
  union { unsigned u; float f; } c; c.u = u & 0xffff0000u; return c.f;
}
// pack two f32 -> two bf16 in one u32 (dst.lo = bf16(a), dst.hi = bf16(b))
__device__ __forceinline__ unsigned cvtpk(float a, float b) {
  unsigned r;
  asm("v_cvt_pk_bf16_f32 %0, %1, %2" : "=v"(r) : "v"(a), "v"(b));
  return r;
}
__device__ __forceinline__ v8s mk8(unsigned a, unsigned b, unsigned c, unsigned d) {
  union { uint4 u; v8s s; } x;
  x.u = make_uint4(a, b, c, d);
  return x.s;
}

// ---------------- K1: emission table E (V x K) + partial Z ----------------
__global__ __launch_bounds__(128, 1)
void k_emis(const float* __restrict__ tag, const float* __restrict__ word,
            const float* __restrict__ bias, float* __restrict__ E,
            float* __restrict__ partialZ, int V) {
  __shared__ float4 wtile[128 * 32];
  __shared__ float btile[128];
  const int tid = threadIdx.x;
  const int v0 = blockIdx.x * 128;

  const float4* w4 = (const float4*)word;
  const int maxi = V * 32 - 1;
#pragma unroll
  for (int it = 0; it < 32; ++it) {
    int idx = it * 128 + tid;
    int g = v0 * 32 + idx;
    wtile[idx] = w4[min(g, maxi)];
  }
  btile[tid] = (v0 + tid < V) ? bias[v0 + tid] : 0.f;

  float treg[128];
  const float4* t4 = (const float4*)(tag + (size_t)tid * 128);
#pragma unroll
  for (int c = 0; c < 32; ++c) {
    float4 x = t4[c];
    treg[4 * c + 0] = x.x; treg[4 * c + 1] = x.y;
    treg[4 * c + 2] = x.z; treg[4 * c + 3] = x.w;
  }
  __syncthreads();

  float zp = 0.f;
  for (int v = 0; v < 128; ++v) {
    if (v0 + v >= V) break;  // uniform
    const float4* row = &wtile[v * 32];
    float a0 = 0.f, a1 = 0.f, a2 = 0.f, a3 = 0.f;
#pragma unroll
    for (int c = 0; c < 32; ++c) {
      float4 pv = row[c];
      a0 = fmaf(pv.x, treg[4 * c + 0], a0);
      a1 = fmaf(pv.y, treg[4 * c + 1], a1);
      a2 = fmaf(pv.z, treg[4 * c + 2], a2);
      a3 = fmaf(pv.w, treg[4 * c + 3], a3);
    }
    float e = __expf((a0 + a1) + (a2 + a3) + btile[v]);
    E[(size_t)(v0 + v) * KK + tid] = e;
    zp += e;
  }
  partialZ[(size_t)blockIdx.x * KK + tid] = zp;
}

// ---------------- K2: transition matrix A2 (K x K) + piZ + piZP ----------
__global__ __launch_bounds__(128)
void k_trans(const float* __restrict__ W, const float* __restrict__ q,
             const float* __restrict__ tb, const float* __restrict__ pZ,
             const float* __restrict__ initlog, float* __restrict__ A2,
             float* __restrict__ piZ, float* __restrict__ piZP, int nPart) {
  __shared__ float qs[KK];
  __shared__ float r0[2], r1[2];
  const int j = threadIdx.x, i = blockIdx.x;
  qs[j] = q[j];
  __syncthreads();

  const float4* w4 = (const float4*)(W + ((size_t)(i * KK + j)) * KK);
  const float4* q4 = (const float4*)qs;
  float a0 = 0.f, a1 = 0.f, a2 = 0.f, a3 = 0.f;
#pragma unroll
  for (int c = 0; c < KK / 4; ++c) {
    float4 wv = w4[c], qv = q4[c];
    a0 = fmaf(wv.x, qv.x, a0); a1 = fmaf(wv.y, qv.y, a1);
    a2 = fmaf(wv.z, qv.z, a2); a3 = fmaf(wv.w, qv.w, a3);
  }
  float logit = (a0 + a1) + (a2 + a3) + tb[i * KK + j];

  float m = wave_max64(logit);
  if ((j & 63) == 0) r0[j >> 6] = m;
  __syncthreads();
  m = fmaxf(r0[0], r0[1]);
  float e = __expf(logit - m);
  float s = wave_sum64(e);
  if ((j & 63) == 0) r1[j >> 6] = s;
  __syncthreads();
  s = r1[0] + r1[1];

  float Z0 = 0.f, Z1 = 0.f, Z2 = 0.f, Z3 = 0.f;
  float Z4 = 0.f, Z5 = 0.f, Z6 = 0.f, Z7 = 0.f;
  int p = 0;
  for (; p + 8 <= nPart; p += 8) {
    Z0 += pZ[(size_t)(p + 0) * KK + j]; Z1 += pZ[(size_t)(p + 1) * KK + j];
    Z2 += pZ[(size_t)(p + 2) * KK + j]; Z3 += pZ[(size_t)(p + 3) * KK + j];
    Z4 += pZ[(size_t)(p + 4) * KK + j]; Z5 += pZ[(size_t)(p + 5) * KK + j];
    Z6 += pZ[(size_t)(p + 6) * KK + j]; Z7 += pZ[(size_t)(p + 7) * KK + j];
  }
  for (; p < nPart; ++p) Z0 += pZ[(size_t)p * KK + j];
  float Z = ((Z0 + Z1) + (Z2 + Z3)) + ((Z4 + Z5) + (Z6 + Z7));

  A2[i * KK + j] = e / (s * Z);

  if (i == 0) {
    float x = initlog[j];
    __syncthreads();
    float m2 = wave_max64(x);
    if ((j & 63) == 0) r0[j >> 6] = m2;
    __syncthreads();
    m2 = fmaxf(r0[0], r0[1]);
    float e2 = __expf(x - m2);
    float s2 = wave_sum64(e2);
    if ((j & 63) == 0) r1[j >> 6] = s2;
    __syncthreads();
    s2 = r1[0] + r1[1];
    float v = e2 / (s2 * Z);
    piZ[j] = v;
    // phi(j): j = 64h+16c+4g+r -> p = 32c+8g+4h+r
    int pp = 32 * ((j >> 4) & 3) + 8 * ((j >> 2) & 3) + 4 * (j >> 6) + (j & 3);
    piZP[pp] = v;
  }
}

// ---------------- K3: em gather, PERMUTED layout ----------------
// emP_u32[(t*BB+b)*64 + q] = bf16(E[tok][jorig(2q)]) | bf16(E[tok][jorig(2q)+1])<<16
// jorig(2q)/2 = 32*((q>>1)&1) + 8*(q>>4) + 2*((q>>2)&3) + (q&1)
__global__ __launch_bounds__(128, 1)
void k_gather(const int* __restrict__ toks, const float* __restrict__ E,
              unsigned* __restrict__ em) {
  const int b = blockIdx.x;        // 0..63
  const int tc = blockIdx.y;       // 0..63 (32 t's each)
  const int q = threadIdx.x & 63;
  const int half = threadIdx.x >> 6;
  const int perm = 32 * ((q >> 1) & 1) + 8 * (q >> 4) + 2 * ((q >> 2) & 3) + (q & 1);
  const float2* E2 = (const float2*)E;
#pragma unroll 4
  for (int it = 0; it < 16; ++it) {
    int t = tc * 32 + it * 2 + half;
    int tok = toks[(size_t)b * TT + t];
    float2 v = E2[(size_t)tok * 64 + perm];
    float sc = ((t & 3) == 0 && (t & 63) != 0) ? 0x1p64f : 1.0f;
    unsigned lo = f2bf(v.x * sc), hi = f2bf(v.y * sc);
    em[((size_t)t * BB + b) * 64 + q] = lo | (hi << 16);
  }
}

// ---------------- K4: barrier-free single-wave MFMA recursion -------------
// 4 blocks x 64 threads (1 wave, 16 batches each). lane l: b=l&15, g=l>>4.
// af[jt][kc] elem e = A2[64(e>>2)+16kc+4g+(e&3)][64(jt>>2)+16(jt&3)+4(m>>2)+(m&3)]
//   (m = l&15); D lane (b,g) acc[jt][r] == alphaP[32(jt&3)+8g+4(jt>>2)+r]
//   == next B-frag[kc=jt&3] elem e=4(jt>>2)+r. Zero shuffles.
template <int S>
__device__ __forceinline__ void hmm_step(int t, const unsigned* __restrict__ emL,
                                         const v8s (&af)[8][4], v8s (&bf)[4],
                                         uint4 (&emQ)[4][4], float& Lacc,
                                         const v4f& ZED) {
  v4f acc[8];
#pragma unroll
  for (int jt = 0; jt < 8; ++jt)
    acc[jt] = __builtin_amdgcn_mfma_f32_16x16x32_bf16(af[jt][0], bf[0], ZED, 0, 0, 0);
#pragma unroll
  for (int kc = 1; kc < 4; ++kc)
#pragma unroll
    for (int jt = 0; jt < 8; ++jt)
      acc[jt] = __builtin_amdgcn_mfma_f32_16x16x32_bf16(af[jt][kc], bf[kc], acc[jt], 0, 0, 0);

  uint4 emv[4];
#pragma unroll
  for (int kc = 0; kc < 4; ++kc) emv[kc] = emQ[S][kc];
  {
    size_t tp = (t + 4 < TT) ? (size_t)(t + 4) : (size_t)(TT - 1);
#pragma unroll
    for (int kc = 0; kc < 4; ++kc)
      emQ[S][kc] = *(const uint4*)(emL + tp * 4096 + 16 * kc);
  }

  float n[8][4];
#pragma unroll
  for (int jt = 0; jt < 8; ++jt) {
    const int kc = jt & 3;
    unsigned q0 = (jt < 4) ? emv[kc].x : emv[kc].z;
    unsigned q1 = (jt < 4) ? emv[kc].y : emv[kc].w;
    n[jt][0] = acc[jt][0] * bflo(q0);
    n[jt][1] = acc[jt][1] * bfhi(q0);
    n[jt][2] = acc[jt][2] * bflo(q1);
    n[jt][3] = acc[jt][3] * bfhi(q1);
  }

  if ((t & 63) == 0) {  // true normalize every 64 steps (uniform branch)
    float sm = 0.f;
#pragma unroll
    for (int jt = 0; jt < 8; ++jt)
      sm += (n[jt][0] + n[jt][1]) + (n[jt][2] + n[jt][3]);
    sm += __shfl_xor(sm, 16, 64);
    sm += __shfl_xor(sm, 32, 64);
    float rc = __builtin_amdgcn_rcpf(sm);
    Lacc += __logf(sm);
#pragma unroll
    for (int jt = 0; jt < 8; ++jt) {
      n[jt][0] *= rc; n[jt][1] *= rc; n[jt][2] *= rc; n[jt][3] *= rc;
    }
  }

#pragma unroll
  for (int kc = 0; kc < 4; ++kc) {
    unsigned u0 = cvtpk(n[kc][0], n[kc][1]);
    unsigned u1 = cvtpk(n[kc][2], n[kc][3]);
    unsigned u2 = cvtpk(n[kc + 4][0], n[kc + 4][1]);
    unsigned u3 = cvtpk(n[kc + 4][2], n[kc + 4][3]);
    bf[kc] = mk8(u0, u1, u2, u3);
  }
}

__global__ __launch_bounds__(64, 1)
void k_fwd_m2(const unsigned* __restrict__ em, const float* __restrict__ A2,
              const float* __restrict__ piZP, float* __restrict__ ll) {
  const int l = threadIdx.x;
  const int b = l & 15;
  const int g = l >> 4;
  const int m = l & 15;
  const int gb = blockIdx.x * 16 + b;

  // static A2 fragments (permuted on both axes), 128 VGPRs
  v8s af[8][4];
#pragma unroll
  for (int jt = 0; jt < 8; ++jt) {
    const int colj = 64 * (jt >> 2) + 16 * (jt & 3) + 4 * (m >> 2) + (m & 3);
#pragma unroll
    for (int kc = 0; kc < 4; ++kc) {
      v8s f;
#pragma unroll
      for (int e = 0; e < 8; ++e) {
        int row = 64 * (e >> 2) + 16 * kc + 4 * g + (e & 3);
        f[e] = (short)f2bf(A2[row * KK + colj]);
      }
      af[jt][kc] = f;
    }
  }

  const unsigned* emL = em + (size_t)gb * 64 + 4 * g;
  const v4f ZED = {0.f, 0.f, 0.f, 0.f};
  float Lacc = 0.f;

  // alphaP0 = piZP * em0  -> initial B-fragments
  v8s bf[4];
#pragma unroll
  for (int kc = 0; kc < 4; ++kc) {
    uint4 ev = *(const uint4*)(emL + 16 * kc);
    float4 pz0 = *(const float4*)(piZP + 32 * kc + 8 * g);
    float4 pz1 = *(const float4*)(piZP + 32 * kc + 8 * g + 4);
    unsigned u0 = cvtpk(pz0.x * bflo(ev.x), pz0.y * bfhi(ev.x));
    unsigned u1 = cvtpk(pz0.z * bflo(ev.y), pz0.w * bfhi(ev.y));
    unsigned u2 = cvtpk(pz1.x * bflo(ev.z), pz1.y * bfhi(ev.z));
    unsigned u3 = cvtpk(pz1.z * bflo(ev.w), pz1.w * bfhi(ev.w));
    bf[kc] = mk8(u0, u1, u2, u3);
  }

  // preload em for t=1..4 (slot = t&3)
  uint4 emQ[4][4];
#pragma unroll
  for (int tp = 1; tp <= 4; ++tp)
#pragma unroll
    for (int kc = 0; kc < 4; ++kc)
      emQ[tp & 3][kc] = *(const uint4*)(emL + (size_t)tp * 4096 + 16 * kc);

  hmm_step<1>(1, emL, af, bf, emQ, Lacc, ZED);
  hmm_step<2>(2, emL, af, bf, emQ, Lacc, ZED);
  hmm_step<3>(3, emL, af, bf, emQ, Lacc, ZED);
  for (int c = 0; c < (TT - 4) / 4; ++c) {
    const int t0 = 4 + 4 * c;
    hmm_step<0>(t0 + 0, emL, af, bf, emQ, Lacc, ZED);
    hmm_step<1>(t0 + 1, emL, af, bf, emQ, Lacc, ZED);
    hmm_step<2>(t0 + 2, emL, af, bf, emQ, Lacc, ZED);
    hmm_step<3>(t0 + 3, emL, af, bf, emQ, Lacc, ZED);
  }

  // final sum over this lane's 32 alpha values (bf16-rounded, ample margin)
  float sm = 0.f;
#pragma unroll
  for (int kc = 0; kc < 4; ++kc) {
    union { v8s s; uint4 u; } x; x.s = bf[kc];
    sm += (bflo(x.u.x) + bfhi(x.u.x)) + (bflo(x.u.y) + bfhi(x.u.y));
    sm += (bflo(x.u.z) + bfhi(x.u.z)) + (bflo(x.u.w) + bfhi(x.u.w));
  }
  sm += __shfl_xor(sm, 16, 64);
  sm += __shfl_xor(sm, 32, 64);
  const float RESCALE_C = (float)(30720.0 * 0.6931471805599453);
  if (l < 16) ll[blockIdx.x * 16 + l] = Lacc + __logf(sm) - RESCALE_C;
}

// ---------------- K4-fallback (round-3 path, used if ws too small) --------
__global__ __launch_bounds__(256, 1)
void k_fwd_fb(const int* __restrict__ toks, const float* __restrict__ E,
              const float* __restrict__ A2, const float* __restrict__ piZ,
              float* __restrict__ ll) {
  __shared__ float pb[2][KK];
  __shared__ float part[2 * KK];
  __shared__ int tk[TT];
  __shared__ float red[4];
  const int tid = threadIdx.x;
  const int j = tid & (KK - 1);
  const int h = tid >> 7;
  const int b = blockIdx.x;

  const int4* t4 = (const int4*)(toks + (size_t)b * TT);
  int4* l4 = (int4*)tk;
#pragma unroll
  for (int c = 0; c < TT / 4 / 256; ++c) l4[c * 256 + tid] = t4[c * 256 + tid];

  float Areg[64];
  {
    const float* Acol = A2 + (size_t)(h * 64) * KK + j;
#pragma unroll
    for (int i = 0; i < 64; ++i) Areg[i] = Acol[i * KK];
  }
  __syncthreads();

  const float* Ej = E + j;
  float eA = Ej[(size_t)tk[1] * KK];
  float eB = Ej[(size_t)tk[2] * KK];
  float eC = Ej[(size_t)tk[3] * KK];
  float eD = Ej[(size_t)tk[4] * KK];
  if (h == 0) pb[0][j] = piZ[j] * Ej[(size_t)tk[0] * KK];
  float Lacc = 0.f;
  __syncthreads();

  for (int t = 1; t < TT; ++t) {
    const float4* ph = (const float4*)&pb[(t - 1) & 1][h * 64];
    float a0 = 0.f, a1 = 0.f, a2 = 0.f, a3 = 0.f;
#pragma unroll
    for (int c = 0; c < 16; ++c) {
      float4 pv = ph[c];
      a0 = fmaf(pv.x, Areg[4 * c + 0], a0);
      a1 = fmaf(pv.y, Areg[4 * c + 1], a1);
      a2 = fmaf(pv.z, Areg[4 * c + 2], a2);
      a3 = fmaf(pv.w, Areg[4 * c + 3], a3);
    }
    part[2 * j + h] = (a0 + a1) + (a2 + a3);
    __syncthreads();

    float e = eA; eA = eB; eB = eC; eC = eD;
    int tn = tk[t + 4 < TT ? t + 4 : TT - 1];
    eD = Ej[(size_t)tn * KK];

    float np = 0.f;
    if (h == 0) {
      float2 pr = *(const float2*)&part[2 * j];
      np = (pr.x + pr.y) * e;
    }
    if ((t & 63) == 0) {
      float v = wave_sum64(np);
      if ((tid & 63) == 0) red[tid >> 6] = v;
      __syncthreads();
      float tot = (red[0] + red[1]) + (red[2] + red[3]);
      np *= __builtin_amdgcn_rcpf(tot);
      if (tid == 0) Lacc += __logf(tot);
    } else if ((t & 3) == 0) {
      np *= 0x1p64f;
    }
    if (h == 0) pb[t & 1][j] = np;
    __syncthreads();
  }

  float lv = (h == 0) ? pb[(TT - 1) & 1][j] : 0.f;
  float v = wave_sum64(lv);
  if ((tid & 63) == 0) red[tid >> 6] = v;
  __syncthreads();
  float tot = (red[0] + red[1]) + (red[2] + red[3]);
  const float RESCALE_C = (float)(30720.0 * 0.6931471805599453);
  if (tid == 0) ll[b] = Lacc + __logf(tot) - RESCALE_C;
}

// ---------------- K5: final reduction ----------------
__global__ void k_final(const float* __restrict__ ll, float* __restrict__ out) {
  float v = ll[threadIdx.x];
  v = wave_sum64(v);
  if (threadIdx.x == 0) out[0] = -v;
}

extern "C" void kernel_launch(void* const* d_in, const int* in_sizes, int n_in,
                              void* d_out, int out_size, void* d_ws, size_t ws_size,
                              hipStream_t stream) {
  const int*   toks    = (const int*)d_in[0];
  const float* initlog = (const float*)d_in[1];
  const float* tag     = (const float*)d_in[2];
  const float* word    = (const float*)d_in[3];
  const float* bias    = (const float*)d_in[4];
  const float* q       = (const float*)d_in[5];
  const float* W       = (const float*)d_in[6];
  const float* tb      = (const float*)d_in[7];
  float* out = (float*)d_out;

  const int V = in_sizes[4];
  const int nPart = (V + 127) / 128;

  float* ws   = (float*)d_ws;
  float* E    = ws;
  float* pZ   = E + (size_t)V * KK;
  float* A2   = pZ + (size_t)nPart * KK;
  float* piZ  = A2 + KK * KK;
  float* piZP = piZ + KK;
  float* ll   = piZP + KK;
  unsigned* em = (unsigned*)(ll + BB);  // TT*BB*64 u32 = 32 MB

  const size_t floats_before_em =
      (size_t)V * KK + (size_t)nPart * KK + KK * KK + 2 * KK + BB;
  const size_t need = floats_before_em * 4 + (size_t)TT * BB * 64 * 4;

  k_emis <<<nPart, 128, 0, stream>>>(tag, word, bias, E, pZ, V);
  k_trans<<<KK, 128, 0, stream>>>(W, q, tb, pZ, initlog, A2, piZ, piZP, nPart);
  if (ws_size >= need) {
    k_gather<<<dim3(BB, TT / 32), 128, 0, stream>>>(toks, E, em);
    k_fwd_m2<<<4, 64, 0, stream>>>(em, A2, piZP, ll);
  } else {
    k_fwd_fb<<<BB, 256, 0, stream>>>(toks, E, A2, piZ, ll);
  }
  k_final<<<1, BB, 0, stream>>>(ll, out);
}